// Round 5
// baseline (82.829 us; speedup 1.0000x reference)
//
#include <hip/hip_runtime.h>

namespace {

constexpr float kDT = 1e-3f;
constexpr int kB = 512;
constexpr int kT = 8192;
constexpr int kChunk = 256;
constexpr int kNC = kT / kChunk;  // 32 chunks per batch row

// Affine transform composition: (later l) o (earlier e)
//   M_out = Ml * Me ; b_out = Ml * be + bl
__device__ __forceinline__ void combine(
    float e0, float e1, float e2, float e3, float e4, float e5,
    float l0, float l1, float l2, float l3, float l4, float l5,
    float& o0, float& o1, float& o2, float& o3, float& o4, float& o5) {
  o0 = l0 * e0 + l1 * e2;
  o1 = l0 * e1 + l1 * e3;
  o2 = l2 * e0 + l3 * e2;
  o3 = l2 * e1 + l3 * e3;
  o4 = l0 * e4 + l1 * e5 + l4;
  o5 = l2 * e4 + l3 * e5 + l5;
}

// Build per-step transform from inputs.
__device__ __forceinline__ void step_transform(
    const float4 xv, const float2 dv,
    float A00, float A01, float A10, float A11,
    float C00, float C01, float C10, float C11,
    float& m0, float& m1, float& m2, float& m3, float& m4, float& m5) {
  // M = I + DT*(A - xic*C)
  m0 = 1.0f + kDT * (A00 - (xv.x * C00 + xv.y * C10));
  m1 =        kDT * (A01 - (xv.x * C01 + xv.y * C11));
  m2 =        kDT * (A10 - (xv.z * C00 + xv.w * C10));
  m3 = 1.0f + kDT * (A11 - (xv.z * C01 + xv.w * C11));
  // b = xic * dy
  m4 = xv.x * dv.x + xv.y * dv.y;
  m5 = xv.z * dv.x + xv.w * dv.y;
}

// Phase 1: per-(batch,chunk) composed transform -> tot[blk*6]
__global__ __launch_bounds__(kChunk) void k_chunk_tot(
    const float* __restrict__ xic, const float* __restrict__ dy,
    const float* __restrict__ Ap, const float* __restrict__ Cp,
    float* __restrict__ tot) {
  __shared__ float s[6][kChunk];
  const int tid = threadIdx.x;
  const int blk = blockIdx.x;          // = b*kNC + c
  const int b = blk / kNC;
  const int c = blk % kNC;
  const size_t t = (size_t)b * kT + (size_t)c * kChunk + tid;

  const float4 xv = reinterpret_cast<const float4*>(xic)[t];
  const float2 dv = reinterpret_cast<const float2*>(dy)[t];
  const float A00 = Ap[0], A01 = Ap[1], A10 = Ap[2], A11 = Ap[3];
  const float C00 = Cp[0], C01 = Cp[1], C10 = Cp[2], C11 = Cp[3];

  float m0, m1, m2, m3, m4, m5;
  step_transform(xv, dv, A00, A01, A10, A11, C00, C01, C10, C11,
                 m0, m1, m2, m3, m4, m5);

  s[0][tid] = m0; s[1][tid] = m1; s[2][tid] = m2;
  s[3][tid] = m3; s[4][tid] = m4; s[5][tid] = m5;
  __syncthreads();

  // Order-preserving pairwise tree reduction (composition is non-commutative).
  for (int n = kChunk; n > 1; n >>= 1) {
    const int half = n >> 1;
    float o0, o1, o2, o3, o4, o5;
    if (tid < half) {
      const int ie = 2 * tid, il = 2 * tid + 1;
      const float e0 = s[0][ie], e1 = s[1][ie], e2 = s[2][ie],
                  e3 = s[3][ie], e4 = s[4][ie], e5 = s[5][ie];
      const float l0 = s[0][il], l1 = s[1][il], l2 = s[2][il],
                  l3 = s[3][il], l4 = s[4][il], l5 = s[5][il];
      combine(e0, e1, e2, e3, e4, e5, l0, l1, l2, l3, l4, l5,
              o0, o1, o2, o3, o4, o5);
    }
    __syncthreads();
    if (tid < half) {
      s[0][tid] = o0; s[1][tid] = o1; s[2][tid] = o2;
      s[3][tid] = o3; s[4][tid] = o4; s[5][tid] = o5;
    }
    __syncthreads();
  }

  if (tid == 0) {
    float* o = tot + (size_t)blk * 6;
    o[0] = s[0][0]; o[1] = s[1][0]; o[2] = s[2][0];
    o[3] = s[3][0]; o[4] = s[4][0]; o[5] = s[5][0];
  }
}

// Phase 2: sequential scan over chunk totals per batch row -> chunk entry states
__global__ void k_scan(const float* __restrict__ tot,
                       float* __restrict__ xinit) {
  const int b = blockIdx.x * blockDim.x + threadIdx.x;
  if (b >= kB) return;
  float x0 = 1.0f, x1 = 0.0f;  // initial_state [1, 0]
  for (int c = 0; c < kNC; ++c) {
    const size_t idx = (size_t)b * kNC + c;
    xinit[idx * 2 + 0] = x0;
    xinit[idx * 2 + 1] = x1;
    const float* m = tot + idx * 6;
    const float n0 = m[0] * x0 + m[1] * x1 + m[4];
    const float n1 = m[2] * x0 + m[3] * x1 + m[5];
    x0 = n0; x1 = n1;
  }
}

// Phase 3: within-chunk exclusive scan -> per-step state -> output
__global__ __launch_bounds__(kChunk) void k_chunk_out(
    const float* __restrict__ xic, const float* __restrict__ dy,
    const float* __restrict__ Ap, const float* __restrict__ Cp,
    const float* __restrict__ xinit, float* __restrict__ out) {
  __shared__ float sa[6][kChunk];
  __shared__ float sb[6][kChunk];
  const int tid = threadIdx.x;
  const int blk = blockIdx.x;          // = b*kNC + c
  const int b = blk / kNC;
  const int c = blk % kNC;
  const size_t t = (size_t)b * kT + (size_t)c * kChunk + tid;

  const float4 xv = reinterpret_cast<const float4*>(xic)[t];
  const float2 dv = reinterpret_cast<const float2*>(dy)[t];
  const float A00 = Ap[0], A01 = Ap[1], A10 = Ap[2], A11 = Ap[3];
  const float C00 = Cp[0], C01 = Cp[1], C10 = Cp[2], C11 = Cp[3];

  float m0, m1, m2, m3, m4, m5;
  step_transform(xv, dv, A00, A01, A10, A11, C00, C01, C10, C11,
                 m0, m1, m2, m3, m4, m5);

  sa[0][tid] = m0; sa[1][tid] = m1; sa[2][tid] = m2;
  sa[3][tid] = m3; sa[4][tid] = m4; sa[5][tid] = m5;
  __syncthreads();

  float (*cur)[kChunk] = sa;
  float (*nxt)[kChunk] = sb;
  // Hillis-Steele inclusive scan over the composition operator.
  for (int d = 1; d < kChunk; d <<= 1) {
    float o0, o1, o2, o3, o4, o5;
    if (tid >= d) {
      const int ie = tid - d;
      const float e0 = cur[0][ie], e1 = cur[1][ie], e2 = cur[2][ie],
                  e3 = cur[3][ie], e4 = cur[4][ie], e5 = cur[5][ie];
      const float l0 = cur[0][tid], l1 = cur[1][tid], l2 = cur[2][tid],
                  l3 = cur[3][tid], l4 = cur[4][tid], l5 = cur[5][tid];
      combine(e0, e1, e2, e3, e4, e5, l0, l1, l2, l3, l4, l5,
              o0, o1, o2, o3, o4, o5);
    } else {
      o0 = cur[0][tid]; o1 = cur[1][tid]; o2 = cur[2][tid];
      o3 = cur[3][tid]; o4 = cur[4][tid]; o5 = cur[5][tid];
    }
    nxt[0][tid] = o0; nxt[1][tid] = o1; nxt[2][tid] = o2;
    nxt[3][tid] = o3; nxt[4][tid] = o4; nxt[5][tid] = o5;
    __syncthreads();
    float (*tmp)[kChunk] = cur; cur = nxt; nxt = tmp;
  }

  // Exclusive prefix for this thread's step (identity for tid==0).
  float ex0, ex1, ex2, ex3, ex4, ex5;
  if (tid == 0) {
    ex0 = 1.0f; ex1 = 0.0f; ex2 = 0.0f; ex3 = 1.0f; ex4 = 0.0f; ex5 = 0.0f;
  } else {
    const int ip = tid - 1;
    ex0 = cur[0][ip]; ex1 = cur[1][ip]; ex2 = cur[2][ip];
    ex3 = cur[3][ip]; ex4 = cur[4][ip]; ex5 = cur[5][ip];
  }

  const float xi0 = xinit[(size_t)blk * 2 + 0];
  const float xi1 = xinit[(size_t)blk * 2 + 1];
  // State entering step t:
  const float x0 = ex0 * xi0 + ex1 * xi1 + ex4;
  const float x1 = ex2 * xi0 + ex3 * xi1 + ex5;

  float2 o;
  o.x = kDT * (C00 * x0 + C01 * x1);
  o.y = kDT * (C10 * x0 + C11 * x1);
  reinterpret_cast<float2*>(out)[t] = o;
}

}  // namespace

extern "C" void kernel_launch(void* const* d_in, const int* in_sizes, int n_in,
                              void* d_out, int out_size, void* d_ws,
                              size_t ws_size, hipStream_t stream) {
  const float* xic = (const float*)d_in[0];   // [B,T,2,2]
  const float* dy  = (const float*)d_in[1];   // [B,T,2]
  const float* Ap  = (const float*)d_in[2];   // [2,2] coeffs_A
  const float* Cp  = (const float*)d_in[3];   // [2,2] C
  float* out = (float*)d_out;                 // [B,T,2]

  float* tot   = (float*)d_ws;                        // kB*kNC*6 floats
  float* xinit = tot + (size_t)kB * kNC * 6;          // kB*kNC*2 floats

  k_chunk_tot<<<kB * kNC, kChunk, 0, stream>>>(xic, dy, Ap, Cp, tot);
  k_scan<<<(kB + 255) / 256, 256, 0, stream>>>(tot, xinit);
  k_chunk_out<<<kB * kNC, kChunk, 0, stream>>>(xic, dy, Ap, Cp, xinit, out);
}

// Round 6
// 35.239 us; speedup vs baseline: 2.3505x; 2.3505x over previous
//
#include <hip/hip_runtime.h>

namespace {

constexpr float kDT = 1e-3f;
constexpr int kB = 512;
constexpr int kT = 8192;
constexpr int kThreads = 1024;
constexpr int kSteps = kT / kThreads;   // 8 consecutive steps per thread
constexpr int kWaves = kThreads / 64;   // 16 waves per block

// Affine transform x' = M x + b packed as {a,b,c,d,p,q}, M=[[a,b],[c,d]], b=(p,q)
struct Xf { float a, b, c, d, p, q; };

// Composition: apply e (earlier) first, then l (later).
__device__ __forceinline__ Xf comp(const Xf& e, const Xf& l) {
  Xf o;
  o.a = l.a * e.a + l.b * e.c;
  o.b = l.a * e.b + l.b * e.d;
  o.c = l.c * e.a + l.d * e.c;
  o.d = l.c * e.b + l.d * e.d;
  o.p = l.a * e.p + l.b * e.q + l.p;
  o.q = l.c * e.p + l.d * e.q + l.q;
  return o;
}

__device__ __forceinline__ Xf shfl_up_xf(const Xf& v, int d) {
  Xf r;
  r.a = __shfl_up(v.a, d);
  r.b = __shfl_up(v.b, d);
  r.c = __shfl_up(v.c, d);
  r.d = __shfl_up(v.d, d);
  r.p = __shfl_up(v.p, d);
  r.q = __shfl_up(v.q, d);
  return r;
}

// One block per batch row. Thread t owns steps [t*8, t*8+8).
// Inputs read once; per-step transforms held in registers; block-level
// affine scan = 8 serial + 6 shuffle rounds + 16-wave LDS stitch.
__global__ __launch_bounds__(kThreads) void k_fused(
    const float* __restrict__ xic, const float* __restrict__ dy,
    const float* __restrict__ Ap, const float* __restrict__ Cp,
    float* __restrict__ out) {
  __shared__ float sWT[kWaves][6];  // wave inclusive totals
  __shared__ float sWE[kWaves][6];  // wave exclusive prefixes

  const int tid = threadIdx.x;
  const int lane = tid & 63;
  const int w = tid >> 6;
  const size_t base = (size_t)blockIdx.x * kT + (size_t)tid * kSteps;

  const float A00 = Ap[0], A01 = Ap[1], A10 = Ap[2], A11 = Ap[3];
  const float C00 = Cp[0], C01 = Cp[1], C10 = Cp[2], C11 = Cp[3];

  // Load this thread's 8 steps (12 independent loads in flight).
  float4 xv[kSteps];
  float2 dv[kSteps];
#pragma unroll
  for (int k = 0; k < kSteps; ++k) {
    xv[k] = reinterpret_cast<const float4*>(xic)[base + k];
    dv[k] = reinterpret_cast<const float2*>(dy)[base + k];
  }

  // Build per-step transforms, keep in registers (static indexing only).
  float m0[kSteps], m1[kSteps], m2[kSteps], m3[kSteps], m4[kSteps], m5[kSteps];
#pragma unroll
  for (int k = 0; k < kSteps; ++k) {
    m0[k] = 1.0f + kDT * (A00 - (xv[k].x * C00 + xv[k].y * C10));
    m1[k] =        kDT * (A01 - (xv[k].x * C01 + xv[k].y * C11));
    m2[k] =        kDT * (A10 - (xv[k].z * C00 + xv[k].w * C10));
    m3[k] = 1.0f + kDT * (A11 - (xv[k].z * C01 + xv[k].w * C11));
    m4[k] = xv[k].x * dv[k].x + xv[k].y * dv[k].y;
    m5[k] = xv[k].z * dv[k].x + xv[k].w * dv[k].y;
  }

  // Serial compose: thread total = m[7] ∘ ... ∘ m[0].
  Xf tot{m0[0], m1[0], m2[0], m3[0], m4[0], m5[0]};
#pragma unroll
  for (int k = 1; k < kSteps; ++k) {
    const Xf s{m0[k], m1[k], m2[k], m3[k], m4[k], m5[k]};
    tot = comp(tot, s);
  }

  // Wave-level inclusive shuffle scan (order = lane order).
  Xf inc = tot;
#pragma unroll
  for (int d = 1; d < 64; d <<= 1) {
    const Xf r = shfl_up_xf(inc, d);
    if (lane >= d) inc = comp(r, inc);
  }

  if (lane == 63) {
    sWT[w][0] = inc.a; sWT[w][1] = inc.b; sWT[w][2] = inc.c;
    sWT[w][3] = inc.d; sWT[w][4] = inc.p; sWT[w][5] = inc.q;
  }
  __syncthreads();

  // Thread 0: exclusive prefixes over the 16 wave totals (15 composes).
  if (tid == 0) {
    Xf pre{1.f, 0.f, 0.f, 1.f, 0.f, 0.f};
    for (int i = 0; i < kWaves; ++i) {
      sWE[i][0] = pre.a; sWE[i][1] = pre.b; sWE[i][2] = pre.c;
      sWE[i][3] = pre.d; sWE[i][4] = pre.p; sWE[i][5] = pre.q;
      const Xf wt{sWT[i][0], sWT[i][1], sWT[i][2],
                  sWT[i][3], sWT[i][4], sWT[i][5]};
      pre = comp(pre, wt);
    }
  }
  __syncthreads();

  const Xf Ew{sWE[w][0], sWE[w][1], sWE[w][2],
              sWE[w][3], sWE[w][4], sWE[w][5]};

  // Lane-exclusive prefix within wave.
  Xf le = shfl_up_xf(inc, 1);
  if (lane == 0) le = Xf{1.f, 0.f, 0.f, 1.f, 0.f, 0.f};

  // Thread-exclusive block prefix = le ∘ Ew (Ew earlier).
  const Xf ex = comp(Ew, le);

  // Row-initial state is (1,0) -> entry state for this thread's run.
  float x0 = ex.a + ex.p;
  float x1 = ex.c + ex.q;

  // Walk 8 steps: emit out_t = DT*C*x (pre-update), then x = M x + b.
#pragma unroll
  for (int k = 0; k < kSteps; ++k) {
    float2 o;
    o.x = kDT * (C00 * x0 + C01 * x1);
    o.y = kDT * (C10 * x0 + C11 * x1);
    reinterpret_cast<float2*>(out)[base + k] = o;
    const float nx0 = m0[k] * x0 + m1[k] * x1 + m4[k];
    const float nx1 = m2[k] * x0 + m3[k] * x1 + m5[k];
    x0 = nx0; x1 = nx1;
  }
}

}  // namespace

extern "C" void kernel_launch(void* const* d_in, const int* in_sizes, int n_in,
                              void* d_out, int out_size, void* d_ws,
                              size_t ws_size, hipStream_t stream) {
  const float* xic = (const float*)d_in[0];  // [B,T,2,2]
  const float* dy  = (const float*)d_in[1];  // [B,T,2]
  const float* Ap  = (const float*)d_in[2];  // [2,2] coeffs_A
  const float* Cp  = (const float*)d_in[3];  // [2,2] C
  float* out = (float*)d_out;                // [B,T,2]

  k_fused<<<kB, kThreads, 0, stream>>>(xic, dy, Ap, Cp, out);
}

// Round 7
// 33.854 us; speedup vs baseline: 2.4467x; 1.0409x over previous
//
#include <hip/hip_runtime.h>

namespace {

constexpr float kDT = 1e-3f;
constexpr int kB = 512;
constexpr int kT = 8192;
constexpr int kThreads = 1024;
constexpr int kWaves = kThreads / 64;     // 16
constexpr int kPassSteps = 2 * kThreads;  // 2048 steps per pass
constexpr int kPasses = kT / kPassSteps;  // 4

// Affine transform x' = M x + b packed {a,b,c,d,p,q}
struct Xf { float a, b, c, d, p, q; };

// Apply e (earlier) first, then l (later).
__device__ __forceinline__ Xf comp(const Xf& e, const Xf& l) {
  Xf o;
  o.a = l.a * e.a + l.b * e.c;
  o.b = l.a * e.b + l.b * e.d;
  o.c = l.c * e.a + l.d * e.c;
  o.d = l.c * e.b + l.d * e.d;
  o.p = l.a * e.p + l.b * e.q + l.p;
  o.q = l.c * e.p + l.d * e.q + l.q;
  return o;
}

__device__ __forceinline__ Xf shfl_up_xf(const Xf& v, int d) {
  Xf r;
  r.a = __shfl_up(v.a, d);
  r.b = __shfl_up(v.b, d);
  r.c = __shfl_up(v.c, d);
  r.d = __shfl_up(v.d, d);
  r.p = __shfl_up(v.p, d);
  r.q = __shfl_up(v.q, d);
  return r;
}

__device__ __forceinline__ Xf make_xf(const float4 xv, float d0, float d1,
                                      float A00, float A01, float A10, float A11,
                                      float C00, float C01, float C10, float C11) {
  Xf m;
  m.a = 1.0f + kDT * (A00 - (xv.x * C00 + xv.y * C10));
  m.b =        kDT * (A01 - (xv.x * C01 + xv.y * C11));
  m.c =        kDT * (A10 - (xv.z * C00 + xv.w * C10));
  m.d = 1.0f + kDT * (A11 - (xv.z * C01 + xv.w * C11));
  m.p = xv.x * d0 + xv.y * d1;
  m.q = xv.z * d0 + xv.w * d1;
  return m;
}

// One block per batch row; 4 passes of 2048 steps; thread owns 2 consecutive
// steps per pass. dy load and out store are single coalesced float4s; xic is
// two float4s at 32B lane stride (16 lines/instr, MSHR-merged).
__global__ __launch_bounds__(kThreads) void k_fused(
    const float* __restrict__ xic, const float* __restrict__ dy,
    const float* __restrict__ Ap, const float* __restrict__ Cp,
    float* __restrict__ out) {
  __shared__ float sWT[kWaves][6];  // wave inclusive totals
  __shared__ float sWI[kWaves][6];  // inclusive scan over wave totals

  const int tid = threadIdx.x;
  const int lane = tid & 63;
  const int w = tid >> 6;
  const size_t rbase = (size_t)blockIdx.x * kT;       // in steps
  const size_t rbase2 = (size_t)blockIdx.x * (kT / 2); // in float4s of dy/out

  const float4* X4 = reinterpret_cast<const float4*>(xic);
  const float4* D4 = reinterpret_cast<const float4*>(dy);
  float4* O4 = reinterpret_cast<float4*>(out);

  const float A00 = Ap[0], A01 = Ap[1], A10 = Ap[2], A11 = Ap[3];
  const float C00 = Cp[0], C01 = Cp[1], C10 = Cp[2], C11 = Cp[3];

  // Double-buffered input registers (indices static after full unroll).
  float4 xva[2], xvb[2], dva[2];

  // Prefetch pass 0.
  {
    const size_t s = (size_t)2 * tid;
    xva[0] = X4[rbase + s];
    xvb[0] = X4[rbase + s + 1];
    dva[0] = D4[rbase2 + tid];
  }

  float x0 = 1.0f, x1 = 0.0f;  // row state entering current pass

#pragma unroll
  for (int c = 0; c < kPasses; ++c) {
    const int buf = c & 1;
    // Prefetch next pass before any barriers/scan of this pass.
    if (c + 1 < kPasses) {
      const size_t s = (size_t)(c + 1) * kPassSteps + 2 * tid;
      xva[buf ^ 1] = X4[rbase + s];
      xvb[buf ^ 1] = X4[rbase + s + 1];
      dva[buf ^ 1] = D4[rbase2 + (size_t)(c + 1) * kThreads + tid];
    }

    // Per-step transforms for this thread's 2 steps.
    const Xf s0 = make_xf(xva[buf], dva[buf].x, dva[buf].y,
                          A00, A01, A10, A11, C00, C01, C10, C11);
    const Xf s1 = make_xf(xvb[buf], dva[buf].z, dva[buf].w,
                          A00, A01, A10, A11, C00, C01, C10, C11);
    const Xf tot = comp(s0, s1);

    // Wave-level inclusive shuffle scan over thread totals.
    Xf inc = tot;
#pragma unroll
    for (int d = 1; d < 64; d <<= 1) {
      const Xf r = shfl_up_xf(inc, d);
      if (lane >= d) inc = comp(r, inc);
    }

    if (lane == 63) {
      sWT[w][0] = inc.a; sWT[w][1] = inc.b; sWT[w][2] = inc.c;
      sWT[w][3] = inc.d; sWT[w][4] = inc.p; sWT[w][5] = inc.q;
    }
    __syncthreads();

    // Wave 0, lanes 0..15: inclusive shuffle scan over the 16 wave totals.
    if (w == 0) {
      Xf v{1.f, 0.f, 0.f, 1.f, 0.f, 0.f};
      if (lane < kWaves) {
        v = Xf{sWT[lane][0], sWT[lane][1], sWT[lane][2],
               sWT[lane][3], sWT[lane][4], sWT[lane][5]};
      }
#pragma unroll
      for (int d = 1; d < kWaves; d <<= 1) {
        const Xf r = shfl_up_xf(v, d);
        if (lane >= d && lane < kWaves) v = comp(r, v);
      }
      if (lane < kWaves) {
        sWI[lane][0] = v.a; sWI[lane][1] = v.b; sWI[lane][2] = v.c;
        sWI[lane][3] = v.d; sWI[lane][4] = v.p; sWI[lane][5] = v.q;
      }
    }
    __syncthreads();

    // Wave-exclusive prefix for this thread's wave.
    Xf Ew{1.f, 0.f, 0.f, 1.f, 0.f, 0.f};
    if (w > 0) {
      Ew = Xf{sWI[w - 1][0], sWI[w - 1][1], sWI[w - 1][2],
              sWI[w - 1][3], sWI[w - 1][4], sWI[w - 1][5]};
    }
    // Lane-exclusive prefix within the wave.
    Xf le = shfl_up_xf(inc, 1);
    if (lane == 0) le = Xf{1.f, 0.f, 0.f, 1.f, 0.f, 0.f};

    const Xf ex = comp(Ew, le);  // block-exclusive prefix for this thread

    // State entering this thread's first step.
    float e0 = ex.a * x0 + ex.b * x1 + ex.p;
    float e1 = ex.c * x0 + ex.d * x1 + ex.q;

    // Emit 2 outputs (pre-update state), advance through s0 then s1.
    float4 o;
    o.x = kDT * (C00 * e0 + C01 * e1);
    o.y = kDT * (C10 * e0 + C11 * e1);
    const float t0 = s0.a * e0 + s0.b * e1 + s0.p;
    const float t1 = s0.c * e0 + s0.d * e1 + s0.q;
    o.z = kDT * (C00 * t0 + C01 * t1);
    o.w = kDT * (C10 * t0 + C11 * t1);
    O4[rbase2 + (size_t)c * kThreads + tid] = o;

    // Advance row state by the whole pass (all threads identically).
    const Xf T{sWI[kWaves - 1][0], sWI[kWaves - 1][1], sWI[kWaves - 1][2],
               sWI[kWaves - 1][3], sWI[kWaves - 1][4], sWI[kWaves - 1][5]};
    const float n0 = T.a * x0 + T.b * x1 + T.p;
    const float n1 = T.c * x0 + T.d * x1 + T.q;
    x0 = n0; x1 = n1;
  }
}

}  // namespace

extern "C" void kernel_launch(void* const* d_in, const int* in_sizes, int n_in,
                              void* d_out, int out_size, void* d_ws,
                              size_t ws_size, hipStream_t stream) {
  const float* xic = (const float*)d_in[0];  // [B,T,2,2]
  const float* dy  = (const float*)d_in[1];  // [B,T,2]
  const float* Ap  = (const float*)d_in[2];  // [2,2] coeffs_A
  const float* Cp  = (const float*)d_in[3];  // [2,2] C
  float* out = (float*)d_out;                // [B,T,2]

  k_fused<<<kB, kThreads, 0, stream>>>(xic, dy, Ap, Cp, out);
}